// Round 1
// baseline (7000.249 us; speedup 1.0000x reference)
//
#include <hip/hip_runtime.h>
#include <math.h>

#define B_    16
#define L_    2048
#define LM1   2047
#define D_    1024
#define H_    512
#define TBLK  64
#define NBLK  32   // ceil(2047/64)

// ---------------------------------------------------------------------------
// K[r][n] = sum_d x[b*L+t][d] * Wcat[n][d],  r = b*LM1 + t, n in [0,1024)
// grid (512, 16), block 256
// ---------------------------------------------------------------------------
__global__ void k_proj(const float* __restrict__ x, const float* __restrict__ Wsem,
                       const float* __restrict__ Wepi, float* __restrict__ K)
{
    __shared__ float As[16][68];
    __shared__ float Bs[16][68];
    const int tid = threadIdx.x;
    const int tx = tid & 15, ty = tid >> 4;
    const int r0 = blockIdx.x * 64;
    const int n0 = blockIdx.y * 64;
    const int lr  = tid >> 2;
    const int lk4 = (tid & 3) << 2;
    const int rowg = r0 + lr;
    const bool rok = rowg < B_ * LM1;
    const int rowc = rok ? rowg : 0;
    const int bb = rowc / LM1;
    const int tt = rowc - bb * LM1;
    const float* xrow = x + ((size_t)bb * L_ + tt) * D_;
    const int nW = n0 + lr;
    const float* wrow = (nW < H_) ? (Wsem + (size_t)nW * D_)
                                  : (Wepi + (size_t)(nW - H_) * D_);
    float acc[4][4];
#pragma unroll
    for (int i = 0; i < 4; ++i)
#pragma unroll
        for (int j = 0; j < 4; ++j) acc[i][j] = 0.f;

    for (int kk = 0; kk < D_; kk += 16) {
        const float4 av = rok ? *(const float4*)(xrow + kk + lk4) : make_float4(0.f,0.f,0.f,0.f);
        const float4 bv = *(const float4*)(wrow + kk + lk4);
        As[lk4+0][lr] = av.x; As[lk4+1][lr] = av.y; As[lk4+2][lr] = av.z; As[lk4+3][lr] = av.w;
        Bs[lk4+0][lr] = bv.x; Bs[lk4+1][lr] = bv.y; Bs[lk4+2][lr] = bv.z; Bs[lk4+3][lr] = bv.w;
        __syncthreads();
#pragma unroll
        for (int k = 0; k < 16; ++k) {
            const float4 a4 = *(const float4*)&As[k][ty << 2];
            const float4 b4 = *(const float4*)&Bs[k][tx << 2];
            const float aa[4] = {a4.x, a4.y, a4.z, a4.w};
            const float bbv[4] = {b4.x, b4.y, b4.z, b4.w};
#pragma unroll
            for (int i = 0; i < 4; ++i)
#pragma unroll
                for (int j = 0; j < 4; ++j)
                    acc[i][j] = fmaf(aa[i], bbv[j], acc[i][j]);
        }
        __syncthreads();
    }
#pragma unroll
    for (int i = 0; i < 4; ++i) {
        const int r = r0 + (ty << 2) + i;
        if (r < B_ * LM1)
            *(float4*)(K + (size_t)r * D_ + n0 + (tx << 2)) =
                make_float4(acc[i][0], acc[i][1], acc[i][2], acc[i][3]);
    }
}

// ---------------------------------------------------------------------------
// squared norms + reciprocal norms per (b, m, t).  grid B_*LM1, block 256
// ---------------------------------------------------------------------------
__global__ void k_norms(const float* __restrict__ K, float* __restrict__ nk2,
                        float* __restrict__ rn)
{
    const int r = blockIdx.x;               // b*LM1 + t
    const int tid = threadIdx.x;            // 256
    const float4 v = *(const float4*)(K + (size_t)r * D_ + (tid << 2));
    float s = v.x*v.x + v.y*v.y + v.z*v.z + v.w*v.w;
#pragma unroll
    for (int o = 32; o; o >>= 1) s += __shfl_xor(s, o);
    __shared__ float part[4];
    const int wid = tid >> 6, lane = tid & 63;
    if (lane == 0) part[wid] = s;
    __syncthreads();
    if (tid == 0) {
        const int b = r / LM1, t = r - b * LM1;
        const float s0 = part[0] + part[1];
        const float s1 = part[2] + part[3];
        nk2[(size_t)(b*2+0)*LM1 + t] = s0;
        nk2[(size_t)(b*2+1)*LM1 + t] = s1;
        rn [(size_t)(b*2+0)*LM1 + t] = 1.f / fmaxf(sqrtf(s0), 1e-12f);
        rn [(size_t)(b*2+1)*LM1 + t] = 1.f / fmaxf(sqrtf(s1), 1e-12f);
    }
}

// ---------------------------------------------------------------------------
// Gram (all blocks, hoisted): G[bm][blk][t][d] = kn_t . kn_{t+d}   (shifted layout)
// grid (NBLK, B_*2), block 256
// ---------------------------------------------------------------------------
__global__ void k_gram(const float* __restrict__ K, const float* __restrict__ rn,
                       float* __restrict__ G)
{
    const int blk = blockIdx.x;
    const int bm  = blockIdx.y;
    const int b = bm >> 1, m = bm & 1;
    const int t0 = blk * TBLK;
    const int Tb = (LM1 - t0 < TBLK) ? (LM1 - t0) : TBLK;
    __shared__ float As[16][68];
    const int tid = threadIdx.x;
    const int tx = tid & 15, ty = tid >> 4;
    const int lr = tid >> 2, lk4 = (tid & 3) << 2;
    const float* Abase = K + ((size_t)(b * LM1 + t0)) * D_ + m * H_;
    float acc[4][4];
#pragma unroll
    for (int i = 0; i < 4; ++i)
#pragma unroll
        for (int j = 0; j < 4; ++j) acc[i][j] = 0.f;

    for (int kk = 0; kk < H_; kk += 16) {
        const float4 av = (lr < Tb) ? *(const float4*)(Abase + (size_t)lr * D_ + kk + lk4)
                                    : make_float4(0.f,0.f,0.f,0.f);
        As[lk4+0][lr] = av.x; As[lk4+1][lr] = av.y; As[lk4+2][lr] = av.z; As[lk4+3][lr] = av.w;
        __syncthreads();
#pragma unroll
        for (int k = 0; k < 16; ++k) {
            const float4 a4 = *(const float4*)&As[k][ty << 2];
            const float4 b4 = *(const float4*)&As[k][tx << 2];
            const float aa[4] = {a4.x, a4.y, a4.z, a4.w};
            const float bbv[4] = {b4.x, b4.y, b4.z, b4.w};
#pragma unroll
            for (int i = 0; i < 4; ++i)
#pragma unroll
                for (int j = 0; j < 4; ++j)
                    acc[i][j] = fmaf(aa[i], bbv[j], acc[i][j]);
        }
        __syncthreads();
    }
    const float* rnb = rn + (size_t)bm * LM1 + t0;
    float* Gout = G + ((size_t)bm * NBLK + blk) * (TBLK * TBLK);
#pragma unroll
    for (int i = 0; i < 4; ++i) {
        const int t = (ty << 2) + i;
        const float rt = (t < Tb) ? rnb[t] : 0.f;
#pragma unroll
        for (int j = 0; j < 4; ++j) {
            const int s = (tx << 2) + j;
            const int d = s - t;
            if (d >= 0) {
                const float val = (t < Tb && s < Tb) ? rt * rnb[s] * acc[i][j] : 0.f;
                Gout[(size_t)t * TBLK + d] = val;
            }
        }
    }
}

// ---------------------------------------------------------------------------
// Vext[bm][t][n] = rn_t * sum_j K[t][j] * M[bm][n][j]     grid (8, B_*2), block 256
// ---------------------------------------------------------------------------
__global__ void k_vext(const float* __restrict__ K, const float* __restrict__ M,
                       const float* __restrict__ rn, float* __restrict__ Vext,
                       int t0, int Tb)
{
    const int bm = blockIdx.y;
    const int b = bm >> 1, m = bm & 1;
    const int n0 = blockIdx.x * 64;
    __shared__ float As[16][68];
    __shared__ float Bs[16][68];
    const int tid = threadIdx.x;
    const int tx = tid & 15, ty = tid >> 4;
    const int lr = tid >> 2, lk4 = (tid & 3) << 2;
    const float* Abase = K + ((size_t)(b * LM1 + t0)) * D_ + m * H_;
    const float* Bbase = M + (size_t)bm * H_ * H_;
    float acc[4][4];
#pragma unroll
    for (int i = 0; i < 4; ++i)
#pragma unroll
        for (int j = 0; j < 4; ++j) acc[i][j] = 0.f;

    for (int kk = 0; kk < H_; kk += 16) {
        const float4 av = (lr < Tb) ? *(const float4*)(Abase + (size_t)lr * D_ + kk + lk4)
                                    : make_float4(0.f,0.f,0.f,0.f);
        const float4 bv = *(const float4*)(Bbase + (size_t)(n0 + lr) * H_ + kk + lk4);
        As[lk4+0][lr] = av.x; As[lk4+1][lr] = av.y; As[lk4+2][lr] = av.z; As[lk4+3][lr] = av.w;
        Bs[lk4+0][lr] = bv.x; Bs[lk4+1][lr] = bv.y; Bs[lk4+2][lr] = bv.z; Bs[lk4+3][lr] = bv.w;
        __syncthreads();
#pragma unroll
        for (int k = 0; k < 16; ++k) {
            const float4 a4 = *(const float4*)&As[k][ty << 2];
            const float4 b4 = *(const float4*)&Bs[k][tx << 2];
            const float aa[4] = {a4.x, a4.y, a4.z, a4.w};
            const float bbv[4] = {b4.x, b4.y, b4.z, b4.w};
#pragma unroll
            for (int i = 0; i < 4; ++i)
#pragma unroll
                for (int j = 0; j < 4; ++j)
                    acc[i][j] = fmaf(aa[i], bbv[j], acc[i][j]);
        }
        __syncthreads();
    }
    const float* rnb = rn + (size_t)bm * LM1 + t0;
#pragma unroll
    for (int i = 0; i < 4; ++i) {
        const int t = (ty << 2) + i;
        if (t < Tb) {
            const float rv = rnb[t];
            *(float4*)(Vext + ((size_t)bm * TBLK + t) * H_ + n0 + (tx << 2)) =
                make_float4(rv*acc[i][0], rv*acc[i][1], rv*acc[i][2], rv*acc[i][3]);
        }
    }
}

// ---------------------------------------------------------------------------
// sequential in-block recurrence.  grid B_, block 512 (thread = component j, both m)
// ---------------------------------------------------------------------------
__global__ void __launch_bounds__(512) k_seq(
    const float* __restrict__ K, const float* __restrict__ Vext,
    const float* __restrict__ G, const float* __restrict__ nk2,
    float* __restrict__ AU, int t0, int Tb, int blk, float omA)
{
    const int b = blockIdx.x;
    const int tid = threadIdx.x;          // 512
    const int wid = tid >> 6, lane = tid & 63;
    __shared__ float Gsh[2 * TBLK * TBLK];
    __shared__ float part[32];
    {
        const float4* s0 = (const float4*)(G + ((size_t)(b*2+0) * NBLK + blk) * (TBLK*TBLK));
        const float4* s1 = (const float4*)(G + ((size_t)(b*2+1) * NBLK + blk) * (TBLK*TBLK));
        float4* dst = (float4*)Gsh;
        dst[tid]        = s0[tid];
        dst[tid + 512]  = s0[tid + 512];
        dst[tid + 1024] = s1[tid];
        dst[tid + 1536] = s1[tid + 512];
    }
    float p0[TBLK], p1[TBLK];
#pragma unroll
    for (int i = 0; i < TBLK; ++i) { p0[i] = 0.f; p1[i] = 0.f; }
    __syncthreads();

    const float* Kb0 = K + ((size_t)(b * LM1 + t0)) * D_ + tid;
    const float* Kb1 = Kb0 + H_;
    const float* Vb0 = Vext + ((size_t)(b*2+0) * TBLK) * H_ + tid;
    const float* Vb1 = Vext + ((size_t)(b*2+1) * TBLK) * H_ + tid;
    float* AU0 = AU + ((size_t)(b*2+0) * TBLK) * H_ + tid;
    float* AU1 = AU + ((size_t)(b*2+1) * TBLK) * H_ + tid;
    const float* q0 = nk2 + (size_t)(b*2+0) * LM1 + t0;
    const float* q1 = nk2 + (size_t)(b*2+1) * LM1 + t0;

    float kc0 = Kb0[0], kc1 = Kb1[0], vc0 = Vb0[0], vc1 = Vb1[0];
    float n0c = q0[0],  n1c = q1[0];

    for (int t = 0; t < Tb; ++t) {
        const float u0 = kc0 - vc0 - p0[0];
        const float u1 = kc1 - vc1 - p1[0];
        float kn0 = 0.f, kn1 = 0.f, vn0 = 0.f, vn1 = 0.f, nn0 = 0.f, nn1 = 0.f;
        if (t + 1 < Tb) {
            kn0 = Kb0[(size_t)(t+1) * D_]; kn1 = Kb1[(size_t)(t+1) * D_];
            vn0 = Vb0[(t+1) * H_];         vn1 = Vb1[(t+1) * H_];
            nn0 = q0[t+1];                 nn1 = q1[t+1];
        }
        float s0 = u0 * u0, s1 = u1 * u1;
#pragma unroll
        for (int o = 32; o; o >>= 1) { s0 += __shfl_xor(s0, o); s1 += __shfl_xor(s1, o); }
        float* pp = &part[(t & 1) << 4];
        if (lane == 0) { pp[wid] = s0; pp[wid + 8] = s1; }
        __syncthreads();
        float Ns = 0.f, Ne = 0.f;
#pragma unroll
        for (int i = 0; i < 8; ++i) { Ns += pp[i]; Ne += pp[i + 8]; }
        const bool fire = (Ns >= 0.49f * n0c) || (Ne >= 0.49f * n1c);
        const float w = (float)(t0 + t + 1) * (1.0f / (float)L_);
        const float vv0 = fire ? omA * u0 : 0.f;
        const float vv1 = fire ? omA * w * u1 : 0.f;
        AU0[(size_t)t * H_] = vv0;
        AU1[(size_t)t * H_] = vv1;
        const float* g0 = Gsh + t * TBLK;
        const float* g1 = Gsh + (TBLK + t) * TBLK;
        if (fire) {
#pragma unroll
            for (int q = 0; q < 16; ++q) {
                const float4 a = ((const float4*)g0)[q];
                const float4 c = ((const float4*)g1)[q];
                const int d0 = q << 2;
                if (q > 0) { p0[d0-1] = fmaf(a.x, vv0, p0[d0]); p1[d0-1] = fmaf(c.x, vv1, p1[d0]); }
                p0[d0+0] = fmaf(a.y, vv0, p0[d0+1]);  p1[d0+0] = fmaf(c.y, vv1, p1[d0+1]);
                p0[d0+1] = fmaf(a.z, vv0, p0[d0+2]);  p1[d0+1] = fmaf(c.z, vv1, p1[d0+2]);
                p0[d0+2] = fmaf(a.w, vv0, p0[d0+3]);  p1[d0+2] = fmaf(c.w, vv1, p1[d0+3]);
            }
        } else {
#pragma unroll
            for (int d = 1; d < TBLK; ++d) { p0[d-1] = p0[d]; p1[d-1] = p1[d]; }
        }
        p0[TBLK-1] = 0.f; p1[TBLK-1] = 0.f;
        kc0 = kn0; kc1 = kn1; vc0 = vn0; vc1 = vn1; n0c = nn0; n1c = nn1;
    }
}

// ---------------------------------------------------------------------------
// M[bm][i][j] += sum_t AU[bm][t][i] * rn_t * K[t][j]      grid (64, B_*2), block 256
// ---------------------------------------------------------------------------
__global__ void k_update(const float* __restrict__ AU, const float* __restrict__ K,
                         const float* __restrict__ rn, float* __restrict__ M,
                         int t0, int Tb)
{
    const int bm = blockIdx.y;
    const int b = bm >> 1, m = bm & 1;
    const int i0 = (blockIdx.x >> 3) * 64;
    const int j0 = (blockIdx.x & 7) * 64;
    __shared__ float As[16][68];
    __shared__ float Bs[16][68];
    const int tid = threadIdx.x;
    const int tx = tid & 15, ty = tid >> 4;
    const int lk = tid >> 4;               // kt within chunk
    const int lc4 = (tid & 15) << 2;       // column
    float acc[4][4];
#pragma unroll
    for (int i = 0; i < 4; ++i)
#pragma unroll
        for (int j = 0; j < 4; ++j) acc[i][j] = 0.f;

    for (int kk = 0; kk < TBLK; kk += 16) {
        const int kt = kk + lk;
        const bool ok = kt < Tb;
        float4 av = ok ? *(const float4*)(AU + ((size_t)bm * TBLK + kt) * H_ + i0 + lc4)
                       : make_float4(0.f,0.f,0.f,0.f);
        const float rv = ok ? rn[(size_t)bm * LM1 + t0 + kt] : 0.f;
        float4 bv = ok ? *(const float4*)(K + ((size_t)(b * LM1 + t0 + kt)) * D_ + m * H_ + j0 + lc4)
                       : make_float4(0.f,0.f,0.f,0.f);
        bv.x *= rv; bv.y *= rv; bv.z *= rv; bv.w *= rv;
        *(float4*)&As[lk][lc4] = av;
        *(float4*)&Bs[lk][lc4] = bv;
        __syncthreads();
#pragma unroll
        for (int k = 0; k < 16; ++k) {
            const float4 a4 = *(const float4*)&As[k][ty << 2];
            const float4 b4 = *(const float4*)&Bs[k][tx << 2];
            const float aa[4] = {a4.x, a4.y, a4.z, a4.w};
            const float bbv[4] = {b4.x, b4.y, b4.z, b4.w};
#pragma unroll
            for (int i = 0; i < 4; ++i)
#pragma unroll
                for (int j = 0; j < 4; ++j)
                    acc[i][j] = fmaf(aa[i], bbv[j], acc[i][j]);
        }
        __syncthreads();
    }
#pragma unroll
    for (int i = 0; i < 4; ++i) {
        float4* p = (float4*)(M + ((size_t)bm * H_ + i0 + (ty << 2) + i) * H_ + j0 + (tx << 2));
        float4 old = *p;
        old.x += acc[i][0]; old.y += acc[i][1]; old.z += acc[i][2]; old.w += acc[i][3];
        *p = old;
    }
}

// ---------------------------------------------------------------------------
// query path: qn (normalized projections) + gnull.  grid B_, block 1024
// ---------------------------------------------------------------------------
__global__ void __launch_bounds__(1024) k_q(
    const float* __restrict__ x, const float* __restrict__ Wsem,
    const float* __restrict__ Wepi, const float* __restrict__ nw,
    const float* __restrict__ nb, float* __restrict__ qn, float* __restrict__ gnull)
{
    const int b = blockIdx.x, tid = threadIdx.x;
    __shared__ float qsh[D_];
    __shared__ float red[16];
    qsh[tid] = x[((size_t)b * L_ + (L_ - 1)) * D_ + tid];
    __syncthreads();
    const float* wrow = (tid < H_) ? (Wsem + (size_t)tid * D_)
                                   : (Wepi + (size_t)(tid - H_) * D_);
    float s = 0.f;
    for (int d = 0; d < D_; d += 4) {
        const float4 w4 = *(const float4*)(wrow + d);
        s += qsh[d]*w4.x + qsh[d+1]*w4.y + qsh[d+2]*w4.z + qsh[d+3]*w4.w;
    }
    float sq = s * s;
#pragma unroll
    for (int o = 32; o; o >>= 1) sq += __shfl_xor(sq, o);
    const int wid = tid >> 6, lane = tid & 63;
    if (lane == 0) red[wid] = sq;
    __syncthreads();
    float n2s = 0.f, n2e = 0.f;
#pragma unroll
    for (int i = 0; i < 8; ++i) { n2s += red[i]; n2e += red[i + 8]; }
    const float rns = 1.f / fmaxf(sqrtf(n2s), 1e-12f);
    const float rne = 1.f / fmaxf(sqrtf(n2e), 1e-12f);
    qn[(size_t)b * D_ + tid] = s * ((tid < H_) ? rns : rne);
    if (wid == 0) {
        float g = 0.f;
        for (int d = lane * 4; d < D_; d += 256) {
            const float4 w4 = *(const float4*)(nw + d);
            g += qsh[d]*w4.x + qsh[d+1]*w4.y + qsh[d+2]*w4.z + qsh[d+3]*w4.w;
        }
#pragma unroll
        for (int o = 32; o; o >>= 1) g += __shfl_xor(g, o);
        if (lane == 0) gnull[b] = 1.f / (1.f + expf(-(g + nb[0])));
    }
}

// ---------------------------------------------------------------------------
// rg[b][n] = gnull[b] * sum_j M[b][m][i][j] qn[b][m*512+j]   grid (16,256), block 256
// ---------------------------------------------------------------------------
__global__ void k_rmv(const float* __restrict__ M, const float* __restrict__ qn,
                      const float* __restrict__ gnull, float* __restrict__ rg)
{
    const int b = blockIdx.x;
    const int n = blockIdx.y * 4 + (threadIdx.x >> 6);
    const int lane = threadIdx.x & 63;
    const int m = n >> 9, i = n & 511;
    const float* Mr = M + ((size_t)(b*2+m) * H_ + i) * H_;
    const float* qv = qn + (size_t)b * D_ + m * H_;
    float s = 0.f;
#pragma unroll
    for (int it = 0; it < 2; ++it) {
        const int j = lane * 4 + it * 256;
        const float4 m4 = *(const float4*)(Mr + j);
        const float4 q4 = *(const float4*)(qv + j);
        s += m4.x*q4.x + m4.y*q4.y + m4.z*q4.z + m4.w*q4.w;
    }
#pragma unroll
    for (int o = 32; o; o >>= 1) s += __shfl_xor(s, o);
    if (lane == 0) rg[(size_t)b * D_ + n] = gnull[b] * s;
}

// ---------------------------------------------------------------------------
// out[b][o] = sum_d rg[b][d] * outw[o][d] + outb[o]        grid (16,256), block 256
// ---------------------------------------------------------------------------
__global__ void k_out(const float* __restrict__ rg, const float* __restrict__ outw,
                      const float* __restrict__ outb, float* __restrict__ out)
{
    const int b = blockIdx.x;
    const int o = blockIdx.y * 4 + (threadIdx.x >> 6);
    const int lane = threadIdx.x & 63;
    const float* wr = outw + (size_t)o * D_;
    const float* rv = rg + (size_t)b * D_;
    float s = 0.f;
#pragma unroll
    for (int it = 0; it < 4; ++it) {
        const int j = lane * 4 + it * 256;
        const float4 w4 = *(const float4*)(wr + j);
        const float4 r4 = *(const float4*)(rv + j);
        s += w4.x*r4.x + w4.y*r4.y + w4.z*r4.z + w4.w*r4.w;
    }
#pragma unroll
    for (int o2 = 32; o2; o2 >>= 1) s += __shfl_xor(s, o2);
    if (lane == 0) out[(size_t)b * D_ + o] = s + outb[o];
}

// ---------------------------------------------------------------------------
extern "C" void kernel_launch(void* const* d_in, const int* in_sizes, int n_in,
                              void* d_out, int out_size, void* d_ws, size_t ws_size,
                              hipStream_t stream)
{
    (void)in_sizes; (void)n_in; (void)out_size;
    const float* x     = (const float*)d_in[0];
    const float* Wsem  = (const float*)d_in[1];
    const float* Wepi  = (const float*)d_in[2];
    const float* nullw = (const float*)d_in[3];
    const float* nullb = (const float*)d_in[4];
    const float* outw  = (const float*)d_in[5];
    const float* outb  = (const float*)d_in[6];
    float* out = (float*)d_out;

    float* ws = (float*)d_ws;
    size_t off = 0;
    float* K     = ws + off; off += (size_t)B_ * LM1 * D_;
    float* nk2   = ws + off; off += (size_t)B_ * 2 * LM1;
    float* rn    = ws + off; off += (size_t)B_ * 2 * LM1;
    float* Mm    = ws + off; off += (size_t)B_ * 2 * H_ * H_;
    float* Vext  = ws + off; off += (size_t)B_ * 2 * TBLK * H_;
    float* G     = ws + off; off += (size_t)B_ * 2 * NBLK * TBLK * TBLK;
    float* AU    = ws + off; off += (size_t)B_ * 2 * TBLK * H_;
    float* qn    = ws + off; off += (size_t)B_ * D_;
    float* gnull = ws + off; off += (size_t)B_;
    float* rg    = ws + off; off += (size_t)B_ * D_;
    if (ws_size < off * sizeof(float)) return;   // insufficient scratch -> fail loudly

    const float omA = (float)(1.0 - pow(0.95, 96.0 / 2048.0));

    hipMemsetAsync(Mm, 0, (size_t)B_ * 2 * H_ * H_ * sizeof(float), stream);

    k_proj <<<dim3(512, 16), 256, 0, stream>>>(x, Wsem, Wepi, K);
    k_norms<<<dim3(B_ * LM1), 256, 0, stream>>>(K, nk2, rn);
    k_gram <<<dim3(NBLK, B_ * 2), 256, 0, stream>>>(K, rn, G);

    for (int blk = 0; blk < NBLK; ++blk) {
        const int t0 = blk * TBLK;
        const int Tb = (LM1 - t0 < TBLK) ? (LM1 - t0) : TBLK;
        k_vext  <<<dim3(8, B_ * 2), 256, 0, stream>>>(K, Mm, rn, Vext, t0, Tb);
        k_seq   <<<dim3(B_), 512, 0, stream>>>(K, Vext, G, nk2, AU, t0, Tb, blk, omA);
        k_update<<<dim3(64, B_ * 2), 256, 0, stream>>>(AU, K, rn, Mm, t0, Tb);
    }

    k_q  <<<dim3(B_), 1024, 0, stream>>>(x, Wsem, Wepi, nullw, nullb, qn, gnull);
    k_rmv<<<dim3(16, 256), 256, 0, stream>>>(Mm, qn, gnull, rg);
    k_out<<<dim3(16, 256), 256, 0, stream>>>(rg, outw, outb, out);
}